// Round 8
// baseline (101.700 us; speedup 1.0000x reference)
//
#include <hip/hip_runtime.h>
#include <hip/hip_bf16.h>

// Problem constants (B,T,C,HS) = (8,4096,1024,64)
#define BB 8
#define TT 4096
#define CC 1024
#define HS 64

typedef __attribute__((ext_vector_type(8))) __bf16 bf16x8;
typedef __attribute__((ext_vector_type(4))) __bf16 bf16x4;
typedef __attribute__((ext_vector_type(4))) float f32x4;

static __device__ __forceinline__ unsigned pack_bf16(float a, float b) {
    unsigned short ua = __builtin_bit_cast(unsigned short, (__bf16)a);
    unsigned short ub = __builtin_bit_cast(unsigned short, (__bf16)b);
    return (unsigned)ua | ((unsigned)ub << 16);
}
static __device__ __forceinline__ unsigned pack_f16(float a, float b) {
    unsigned short ua = __builtin_bit_cast(unsigned short, (_Float16)a);
    unsigned short ub = __builtin_bit_cast(unsigned short, (_Float16)b);
    return (unsigned)ua | ((unsigned)ub << 16);
}
static __device__ __forceinline__ float h2f(unsigned short u) {
    return (float)__builtin_bit_cast(_Float16, u);
}

// ---------------------------------------------------------------------------
// Kernel 0: W prep.  Wt[192][1024] bf16 = [Wq^T * 0.125*log2(e) | Wk^T | Wv^T]
// ---------------------------------------------------------------------------
__global__ __launch_bounds__(256) void wprep_kernel(
    const float* __restrict__ Wq, const float* __restrict__ Wk,
    const float* __restrict__ Wv, __bf16* __restrict__ Wt)
{
    int i = blockIdx.x * 256 + threadIdx.x;
    int dr = i >> 10;
    int c  = i & 1023;
    int m  = dr >> 6;
    int d  = dr & 63;
    const float* src = (m == 0) ? Wq : ((m == 1) ? Wk : Wv);
    float v = src[(long)c * HS + d];
    if (m == 0) v *= 0.125f * 1.4426950408889634f;   // scale * log2e into Wq
    Wt[i] = (__bf16)v;
}

// ---------------------------------------------------------------------------
// Kernel 1: QKV projection + RoPE.  One block = 64 token rows, 4 waves x 16.
// Q,K stored row-major [t][d]; V stored TRANSPOSED Vt[b*64+d][t] (via LDS).
// ---------------------------------------------------------------------------
__global__ __launch_bounds__(256) void qkv_rope_kernel(
    const float* __restrict__ x,     // [B*T][C]
    const float* __restrict__ cosT,  // [T][32]
    const float* __restrict__ sinT,  // [T][32]
    const __bf16* __restrict__ Wt,   // [192][1024]
    __bf16* __restrict__ Qo, __bf16* __restrict__ Ko, __bf16* __restrict__ Vo)
{
    __shared__ __bf16 xs[64][72];
    __shared__ __bf16 Wl[192][72];

    const int tid  = threadIdx.x;
    const int lane = tid & 63;
    const int w    = tid >> 6;
    const int col  = lane & 15;
    const int grp  = lane >> 4;
    const long rowbase = (long)blockIdx.x * 64;

    f32x4 acc[12];
#pragma unroll
    for (int i = 0; i < 12; i++) acc[i] = 0.0f;

    for (int ck = 0; ck < CC; ck += 64) {
        {
            int r = tid >> 2, c0 = (tid & 3) * 16;
            const float4* src = (const float4*)(x + (rowbase + r) * (long)CC + ck + c0);
#pragma unroll
            for (int i = 0; i < 4; i++) {
                float4 v = src[i];
                bf16x4 t;
                t[0] = (__bf16)v.x; t[1] = (__bf16)v.y;
                t[2] = (__bf16)v.z; t[3] = (__bf16)v.w;
                *(bf16x4*)&xs[r][c0 + i * 4] = t;
            }
        }
        {
#pragma unroll
            for (int i = 0; i < 6; i++) {
                int u = i * 256 + tid;
                int dr = u >> 3, cu = (u & 7) * 8;
                bf16x8 v = *(const bf16x8*)(Wt + (long)dr * CC + ck + cu);
                *(bf16x8*)&Wl[dr][cu] = v;
            }
        }
        __syncthreads();
#pragma unroll
        for (int s = 0; s < 2; s++) {
            bf16x8 a = *(const bf16x8*)&xs[w * 16 + col][s * 32 + grp * 8];
#pragma unroll
            for (int nf = 0; nf < 12; nf++) {
                bf16x8 b = *(const bf16x8*)&Wl[nf * 16 + col][s * 32 + grp * 8];
                acc[nf] = __builtin_amdgcn_mfma_f32_16x16x32_bf16(a, b, acc[nf], 0, 0, 0);
            }
        }
        __syncthreads();
    }

#pragma unroll
    for (int r = 0; r < 4; r++) {
        long grow = rowbase + w * 16 + grp * 4 + r;
        int t = (int)(grow & (TT - 1));
        const float* cp = cosT + (long)t * 32;
        const float* sp = sinT + (long)t * 32;
#pragma unroll
        for (int nf = 0; nf < 4; nf++) {
            int ii = nf * 8 + (col >> 1);
            float cs = cp[ii], sn = sp[ii];
            float sgn_sn = (col & 1) ? sn : -sn;
            float qv = acc[nf][r];
            float qp = __shfl_xor(qv, 1);
            float qo = qv * cs + qp * sgn_sn;
            float kv = acc[nf + 4][r];
            float kp = __shfl_xor(kv, 1);
            float ko = kv * cs + kp * sgn_sn;
            long base = grow * HS + nf * 16 + col;
            Qo[base] = (__bf16)qo;
            Ko[base] = (__bf16)ko;
            xs[nf * 16 + col][w * 16 + grp * 4 + r] = (__bf16)acc[nf + 8][r];
        }
    }
    __syncthreads();
    {
        int d = tid >> 2, seg = tid & 3;
        int b  = (int)(rowbase >> 12);
        int t0 = (int)(rowbase & (TT - 1));
        bf16x8 v0 = *(const bf16x8*)&xs[d][seg * 16];
        bf16x8 v1 = *(const bf16x8*)&xs[d][seg * 16 + 8];
        __bf16* dst = Vo + ((size_t)b * 64 + d) * TT + t0 + seg * 16;
        *(bf16x8*)dst = v0;
        *(bf16x8*)(dst + 8) = v1;
    }
}

// ---------------------------------------------------------------------------
// Kernel 2: causal flash attention, 128-row q-tiles, QBLK=32 per wave
// (2 q-subtiles of 16), LDS-shared K/V, 2-phase double buffer, 2-way split-K.
// Block n: b=n&7, j=n>>3 (0..63):
//   j<32 : Qt=31-j, ch0 = kv tiles [0, Qt+1)        (size Qt+1, heavy-first)
//   else : Qt=j-32, ch1 = kv tiles [Qt+1, 2Qt+2)    (size Qt+1)
// CU c hosts j=c and j=c+32: (32-c) + (c+1) = 33 tiles, always.
// All blocks write l-normalized f16 partials + (m,l); combine merges 2 chunks.
// ---------------------------------------------------------------------------
__global__ __launch_bounds__(256, 2) void attn_kernel(
    const __bf16* __restrict__ Q, const __bf16* __restrict__ K,
    const __bf16* __restrict__ Vt,
    _Float16* __restrict__ Opart, float* __restrict__ mlbuf)
{
    __shared__ __bf16 Kl[2][64 * 64];                  // swizzled image, 8KB each
    __shared__ __bf16 Vl[2][64 * 64];
    __shared__ __align__(16) unsigned char plds[4][2][2048];

    const int tid  = threadIdx.x;
    const int lane = tid & 63;
    const int col  = lane & 15;
    const int g    = lane >> 4;
    const int w    = tid >> 6;

    const int n = blockIdx.x;
    const int b = n & 7;
    const int j_ = n >> 3;
    int Qt, ch, j0, j1;
    if (j_ < 32) { Qt = 31 - j_; ch = 0; j0 = 0;      j1 = Qt + 1; }
    else         { Qt = j_ - 32; ch = 1; j0 = Qt + 1; j1 = 2 * Qt + 2; }

    const int qbase = Qt * 128 + w * 32;               // wave's first q row
    const size_t qgrow = (size_t)b * TT + qbase;
    bf16x8 qb[2][2];
#pragma unroll
    for (int sub = 0; sub < 2; sub++)
#pragma unroll
        for (int s = 0; s < 2; s++)
            qb[sub][s] = *(const bf16x8*)(Q + (qgrow + sub * 16 + col) * HS + s * 32 + g * 8);

    // stage-thread geometry: thread handles 16B chunks (r0,c0) and (r1,c0)
    const int r0 = tid >> 3, c0 = tid & 7;
    const int r1 = r0 + 32;
    const __bf16* Kbase = K + (size_t)b * TT * HS;
    const __bf16* Vbase = Vt + (size_t)b * 64 * TT;

#define SWZ(row, cb) (((row) << 6) | (((cb) ^ ((row) & 7)) << 3))

    f32x4 acc[2][4];
#pragma unroll
    for (int sub = 0; sub < 2; sub++)
#pragma unroll
        for (int i = 0; i < 4; i++) acc[sub][i] = 0.f;
    float mrun[2] = { -3e38f, -3e38f };
    float lsum[2][4] = { {0.f,0.f,0.f,0.f}, {0.f,0.f,0.f,0.f} };

    const int sw = col & 7;

    bf16x8 sk0, sk1, sv0, sv1;                          // staging registers
    auto stageLoad = [&](int j) {
        const __bf16* kp = Kbase + (size_t)(j * 64) * HS;
        sk0 = *(const bf16x8*)(kp + r0 * HS + c0 * 8);
        sk1 = *(const bf16x8*)(kp + r1 * HS + c0 * 8);
        const __bf16* vp = Vbase + j * 64;
        sv0 = *(const bf16x8*)(vp + (size_t)r0 * TT + c0 * 8);
        sv1 = *(const bf16x8*)(vp + (size_t)r1 * TT + c0 * 8);
    };
    auto stageWrite = [&](int buf) {
        *(bf16x8*)&Kl[buf][SWZ(r0, c0)] = sk0;
        *(bf16x8*)&Kl[buf][SWZ(r1, c0)] = sk1;
        *(bf16x8*)&Vl[buf][SWZ(r0, c0)] = sv0;
        *(bf16x8*)&Vl[buf][SWZ(r1, c0)] = sv1;
    };

    // ---- prologue ----
    stageLoad(j0);
    stageWrite(0);
    __syncthreads();

    int cur = 0;
    for (int j = j0; j < j1; ++j) {
        const bool more = (j + 1 < j1);
        if (more) stageLoad(j + 1);                     // T14: issue loads EARLY
        __builtin_amdgcn_sched_barrier(0);              // pin loads above compute

        // ---- K fragments once, shared by both q-subtiles ----
        bf16x8 kf[8];
#pragma unroll
        for (int nf = 0; nf < 4; nf++)
#pragma unroll
            for (int s = 0; s < 2; s++)
                kf[nf * 2 + s] = *(const bf16x8*)&Kl[cur][SWZ(nf * 16 + col, s * 4 + g)];

#pragma unroll
        for (int sub = 0; sub < 2; sub++) {
            if (j * 64 > qbase + sub * 16) continue;    // fully-masked: exact skip
            f32x4 sf[4];
#pragma unroll
            for (int i = 0; i < 4; i++) sf[i] = 0.f;
            __builtin_amdgcn_s_setprio(1);
#pragma unroll
            for (int s = 0; s < 2; s++)
#pragma unroll
                for (int nf = 0; nf < 4; nf++)
                    sf[nf] = __builtin_amdgcn_mfma_f32_16x16x32_bf16(kf[nf * 2 + s], qb[sub][s], sf[nf], 0, 0, 0);
            __builtin_amdgcn_s_setprio(0);
            // ---- causal mask (only tiles in the diagonal band) ----
            if (j >= 2 * Qt) {
                const int qloc = qbase + sub * 16 + col;
#pragma unroll
                for (int nf = 0; nf < 4; nf++)
#pragma unroll
                    for (int r = 0; r < 4; r++)
                        if (j * 64 + nf * 16 + g * 4 + r > qloc) sf[nf][r] = -3e38f;
            }
            // ---- per-lane tree max over 16 values ----
            float fm[4];
#pragma unroll
            for (int f = 0; f < 4; f++)
                fm[f] = fmaxf(fmaxf(sf[f][0], sf[f][1]), fmaxf(sf[f][2], sf[f][3]));
            float mt = fmaxf(fmaxf(fm[0], fm[1]), fmaxf(fm[2], fm[3]));
            // ---- defer-max (THR=8 in exp2 units) ----
            if (!__all(mt <= mrun[sub] + 8.0f)) {
                float mg = fmaxf(mt, __shfl_xor(mt, 16));
                mg = fmaxf(mg, __shfl_xor(mg, 32));
                float mn = fmaxf(mrun[sub], mg);
                float al = exp2f(mrun[sub] - mn);
                mrun[sub] = mn;
#pragma unroll
                for (int q = 0; q < 4; q++) lsum[sub][q] *= al;
#pragma unroll
                for (int nf = 0; nf < 4; nf++) acc[sub][nf] *= al;
            }
            // ---- exp + per-lane partial sums ----
#pragma unroll
            for (int f = 0; f < 4; f++) {
                float p0 = exp2f(sf[f][0] - mrun[sub]);
                float p1 = exp2f(sf[f][1] - mrun[sub]);
                float p2 = exp2f(sf[f][2] - mrun[sub]);
                float p3 = exp2f(sf[f][3] - mrun[sub]);
                sf[f][0] = p0; sf[f][1] = p1; sf[f][2] = p2; sf[f][3] = p3;
                lsum[sub][0] += p0; lsum[sub][1] += p1;
                lsum[sub][2] += p2; lsum[sub][3] += p3;
            }
            // ---- P^T -> P rows via wave-private swizzled LDS bounce ----
            unsigned char* pb = &plds[w][sub][0] + col * 128;
#pragma unroll
            for (int nf = 0; nf < 4; nf++) {
                uint2 val;
                val.x = pack_bf16(sf[nf][0], sf[nf][1]);
                val.y = pack_bf16(sf[nf][2], sf[nf][3]);
                *(uint2*)(pb + ((((nf * 2 + (g >> 1)) ^ sw) << 4) | ((g & 1) << 3))) = val;
            }
        }

        // ---- V fragments once, shared by both q-subtiles ----
        bf16x8 vf[8];
#pragma unroll
        for (int nf = 0; nf < 4; nf++)
#pragma unroll
            for (int s = 0; s < 2; s++)
                vf[nf * 2 + s] = *(const bf16x8*)&Vl[cur][SWZ(nf * 16 + col, s * 4 + g)];

#pragma unroll
        for (int sub = 0; sub < 2; sub++) {
            if (j * 64 > qbase + sub * 16) continue;
            unsigned char* pb = &plds[w][sub][0] + col * 128;
            __builtin_amdgcn_s_setprio(1);
#pragma unroll
            for (int s = 0; s < 2; s++) {
                bf16x8 pf = *(const bf16x8*)(pb + (((s * 4 + g) ^ sw) << 4));
#pragma unroll
                for (int nf = 0; nf < 4; nf++)
                    acc[sub][nf] = __builtin_amdgcn_mfma_f32_16x16x32_bf16(vf[nf * 2 + s], pf, acc[sub][nf], 0, 0, 0);
            }
            __builtin_amdgcn_s_setprio(0);
        }

        if (more) stageWrite(cur ^ 1);
        __syncthreads();
        cur ^= 1;
    }

    // ---- epilogue: l-normalized f16 partial + (m,l) per row ----
    const size_t slot = (size_t)(b * 32 + Qt) * 2 + ch;
#pragma unroll
    for (int sub = 0; sub < 2; sub++) {
        float ls = (lsum[sub][0] + lsum[sub][1]) + (lsum[sub][2] + lsum[sub][3]);
        ls += __shfl_xor(ls, 16);
        ls += __shfl_xor(ls, 32);
        float rinv = (ls > 0.f) ? __builtin_amdgcn_rcpf(ls) : 0.f;
        const int rowg = w * 32 + sub * 16 + col;
        _Float16* prow = Opart + slot * 8192 + (size_t)rowg * 64;
#pragma unroll
        for (int nf = 0; nf < 4; nf++) {
            uint2 v;
            v.x = pack_f16(acc[sub][nf][0] * rinv, acc[sub][nf][1] * rinv);
            v.y = pack_f16(acc[sub][nf][2] * rinv, acc[sub][nf][3] * rinv);
            *(uint2*)(prow + nf * 16 + g * 4) = v;
        }
        if (g == 0) {
            float2 mv = make_float2(mrun[sub], ls);
            *(float2*)(mlbuf + (slot * 128 + rowg) * 2) = mv;
        }
    }
#undef SWZ
}

// ---------------------------------------------------------------------------
// Kernel 3: combine the two split-K partial chunks for every 128-row q-tile.
// ---------------------------------------------------------------------------
__global__ __launch_bounds__(256) void combine_kernel(
    const _Float16* __restrict__ Opart, const float* __restrict__ mlbuf,
    float* __restrict__ O)
{
    const int Qt = blockIdx.x;             // 0..31
    const int b  = blockIdx.y;
    const int row = threadIdx.x >> 1;      // 0..127
    const int seg = threadIdx.x & 1;       // 32 dims each
    const size_t slot0 = (size_t)(b * 32 + Qt) * 2;

    const float* p0 = mlbuf + ((slot0 + 0) * 128 + row) * 2;
    const float* p1 = mlbuf + ((slot0 + 1) * 128 + row) * 2;
    float m0 = p0[0], l0 = p0[1];
    float m1 = p1[0], l1 = p1[1];
    float M  = fmaxf(m0, m1);
    float w0 = l0 * exp2f(m0 - M);
    float w1 = l1 * exp2f(m1 - M);
    float rinv = 1.0f / (w0 + w1);
    w0 *= rinv; w1 *= rinv;

    const uint4* s0 = (const uint4*)(Opart + (slot0 + 0) * 8192 + (size_t)row * 64 + seg * 32);
    const uint4* s1 = (const uint4*)(Opart + (slot0 + 1) * 8192 + (size_t)row * 64 + seg * 32);
    float* dst = O + ((size_t)b * TT + Qt * 128 + row) * 64 + seg * 32;
#pragma unroll
    for (int i = 0; i < 4; i++) {
        uint4 a = s0[i], c = s1[i];
        float4 v;
        v.x = h2f((unsigned short)(a.x      )) * w0 + h2f((unsigned short)(c.x      )) * w1;
        v.y = h2f((unsigned short)(a.x >> 16)) * w0 + h2f((unsigned short)(c.x >> 16)) * w1;
        v.z = h2f((unsigned short)(a.y      )) * w0 + h2f((unsigned short)(c.y      )) * w1;
        v.w = h2f((unsigned short)(a.y >> 16)) * w0 + h2f((unsigned short)(c.y >> 16)) * w1;
        *(float4*)(dst + i * 8) = v;
        float4 u;
        u.x = h2f((unsigned short)(a.z      )) * w0 + h2f((unsigned short)(c.z      )) * w1;
        u.y = h2f((unsigned short)(a.z >> 16)) * w0 + h2f((unsigned short)(c.z >> 16)) * w1;
        u.z = h2f((unsigned short)(a.w      )) * w0 + h2f((unsigned short)(c.w      )) * w1;
        u.w = h2f((unsigned short)(a.w >> 16)) * w0 + h2f((unsigned short)(c.w >> 16)) * w1;
        *(float4*)(dst + i * 8 + 4) = u;
    }
}

// ---------------------------------------------------------------------------
extern "C" void kernel_launch(void* const* d_in, const int* in_sizes, int n_in,
                              void* d_out, int out_size, void* d_ws, size_t ws_size,
                              hipStream_t stream)
{
    const float* x    = (const float*)d_in[0];
    const float* cosT = (const float*)d_in[1];
    const float* sinT = (const float*)d_in[2];
    const float* Wq   = (const float*)d_in[3];
    const float* Wk   = (const float*)d_in[4];
    const float* Wv   = (const float*)d_in[5];
    float* out = (float*)d_out;

    __bf16* Qb = (__bf16*)d_ws;
    __bf16* Kb = Qb + (size_t)BB * TT * HS;
    __bf16* Vb = Kb + (size_t)BB * TT * HS;   // transposed: [b*64+d][t]
    __bf16* Wt = Vb + (size_t)BB * TT * HS;

    const size_t base_bytes = (size_t)3 * BB * TT * HS * 2 + 192 * 1024 * 2;
    _Float16* Opart = (_Float16*)((char*)d_ws + ((base_bytes + 255) & ~(size_t)255));
    float* mlbuf = (float*)(Opart + (size_t)512 * 8192);   // 8.39MB of f16 partials

    wprep_kernel<<<(192 * 1024) / 256, 256, 0, stream>>>(Wq, Wk, Wv, Wt);
    qkv_rope_kernel<<<(BB * TT) / 64, 256, 0, stream>>>(x, cosT, sinT, Wt, Qb, Kb, Vb);
    attn_kernel<<<512, 256, 0, stream>>>(Qb, Kb, Vb, Opart, mlbuf);
    combine_kernel<<<dim3(32, 8), 256, 0, stream>>>(Opart, mlbuf, out);
}

// Round 9
// 84.160 us; speedup vs baseline: 1.2084x; 1.2084x over previous
//
#include <hip/hip_runtime.h>
#include <hip/hip_bf16.h>

// Problem constants (B,T,C,HS) = (8,4096,1024,64)
#define BB 8
#define TT 4096
#define CC 1024
#define HS 64

typedef __attribute__((ext_vector_type(8))) __bf16 bf16x8;
typedef __attribute__((ext_vector_type(4))) __bf16 bf16x4;
typedef __attribute__((ext_vector_type(4))) float f32x4;

static __device__ __forceinline__ unsigned pack_bf16(float a, float b) {
    unsigned short ua = __builtin_bit_cast(unsigned short, (__bf16)a);
    unsigned short ub = __builtin_bit_cast(unsigned short, (__bf16)b);
    return (unsigned)ua | ((unsigned)ub << 16);
}

// ---------------------------------------------------------------------------
// Kernel 0: W prep.  Wt[192][1024] bf16 = [Wq^T * 0.125*log2(e) | Wk^T | Wv^T]
// ---------------------------------------------------------------------------
__global__ __launch_bounds__(256) void wprep_kernel(
    const float* __restrict__ Wq, const float* __restrict__ Wk,
    const float* __restrict__ Wv, __bf16* __restrict__ Wt)
{
    int i = blockIdx.x * 256 + threadIdx.x;
    int dr = i >> 10;
    int c  = i & 1023;
    int m  = dr >> 6;
    int d  = dr & 63;
    const float* src = (m == 0) ? Wq : ((m == 1) ? Wk : Wv);
    float v = src[(long)c * HS + d];
    if (m == 0) v *= 0.125f * 1.4426950408889634f;   // scale * log2e into Wq
    Wt[i] = (__bf16)v;
}

// ---------------------------------------------------------------------------
// Kernel 1: QKV projection + RoPE.  One block = 64 token rows, 4 waves x 16.
// Q,K stored row-major [t][d]; V stored TRANSPOSED Vt[b*64+d][t] (via LDS).
// ---------------------------------------------------------------------------
__global__ __launch_bounds__(256) void qkv_rope_kernel(
    const float* __restrict__ x,     // [B*T][C]
    const float* __restrict__ cosT,  // [T][32]
    const float* __restrict__ sinT,  // [T][32]
    const __bf16* __restrict__ Wt,   // [192][1024]
    __bf16* __restrict__ Qo, __bf16* __restrict__ Ko, __bf16* __restrict__ Vo)
{
    __shared__ __bf16 xs[64][72];
    __shared__ __bf16 Wl[192][72];

    const int tid  = threadIdx.x;
    const int lane = tid & 63;
    const int w    = tid >> 6;
    const int col  = lane & 15;
    const int grp  = lane >> 4;
    const long rowbase = (long)blockIdx.x * 64;

    f32x4 acc[12];
#pragma unroll
    for (int i = 0; i < 12; i++) acc[i] = 0.0f;

    for (int ck = 0; ck < CC; ck += 64) {
        {
            int r = tid >> 2, c0 = (tid & 3) * 16;
            const float4* src = (const float4*)(x + (rowbase + r) * (long)CC + ck + c0);
#pragma unroll
            for (int i = 0; i < 4; i++) {
                float4 v = src[i];
                bf16x4 t;
                t[0] = (__bf16)v.x; t[1] = (__bf16)v.y;
                t[2] = (__bf16)v.z; t[3] = (__bf16)v.w;
                *(bf16x4*)&xs[r][c0 + i * 4] = t;
            }
        }
        {
#pragma unroll
            for (int i = 0; i < 6; i++) {
                int u = i * 256 + tid;
                int dr = u >> 3, cu = (u & 7) * 8;
                bf16x8 v = *(const bf16x8*)(Wt + (long)dr * CC + ck + cu);
                *(bf16x8*)&Wl[dr][cu] = v;
            }
        }
        __syncthreads();
#pragma unroll
        for (int s = 0; s < 2; s++) {
            bf16x8 a = *(const bf16x8*)&xs[w * 16 + col][s * 32 + grp * 8];
#pragma unroll
            for (int nf = 0; nf < 12; nf++) {
                bf16x8 b = *(const bf16x8*)&Wl[nf * 16 + col][s * 32 + grp * 8];
                acc[nf] = __builtin_amdgcn_mfma_f32_16x16x32_bf16(a, b, acc[nf], 0, 0, 0);
            }
        }
        __syncthreads();
    }

#pragma unroll
    for (int r = 0; r < 4; r++) {
        long grow = rowbase + w * 16 + grp * 4 + r;
        int t = (int)(grow & (TT - 1));
        const float* cp = cosT + (long)t * 32;
        const float* sp = sinT + (long)t * 32;
#pragma unroll
        for (int nf = 0; nf < 4; nf++) {
            int ii = nf * 8 + (col >> 1);
            float cs = cp[ii], sn = sp[ii];
            float sgn_sn = (col & 1) ? sn : -sn;
            float qv = acc[nf][r];
            float qp = __shfl_xor(qv, 1);
            float qo = qv * cs + qp * sgn_sn;
            float kv = acc[nf + 4][r];
            float kp = __shfl_xor(kv, 1);
            float ko = kv * cs + kp * sgn_sn;
            long base = grow * HS + nf * 16 + col;
            Qo[base] = (__bf16)qo;
            Ko[base] = (__bf16)ko;
            xs[nf * 16 + col][w * 16 + grp * 4 + r] = (__bf16)acc[nf + 8][r];
        }
    }
    __syncthreads();
    {
        int d = tid >> 2, seg = tid & 3;
        int b  = (int)(rowbase >> 12);
        int t0 = (int)(rowbase & (TT - 1));
        bf16x8 v0 = *(const bf16x8*)&xs[d][seg * 16];
        bf16x8 v1 = *(const bf16x8*)&xs[d][seg * 16 + 8];
        __bf16* dst = Vo + ((size_t)b * 64 + d) * TT + t0 + seg * 16;
        *(bf16x8*)dst = v0;
        *(bf16x8*)(dst + 8) = v1;
    }
}

// ---------------------------------------------------------------------------
// Kernel 2: causal flash attention, LDS-shared K/V, split-K (R7 balance),
// T15 two-tile pipeline: iteration j runs QK(j) on the matrix pipe while
// finishing (softmax+PV) tile j-1 on VALU/LDS.  K 2-buffered, V 3-buffered,
// ONE __syncthreads per tile.
// Block n: b=n&7, idx=n>>3 in 0..95:
//   idx<32 : qt=32+idx, tiles [0,32)      -> partial ch0   (32 tiles)
//   idx<64 : qt=idx,    tiles [32,qt]     -> partial ch1   (idx-31 tiles)
//   else   : qt=95-idx, tiles [0,qt]      -> direct write  (96-idx tiles)
// ---------------------------------------------------------------------------
__global__ __launch_bounds__(256, 3) void attn_kernel(
    const __bf16* __restrict__ Q, const __bf16* __restrict__ K,
    const __bf16* __restrict__ Vt, float* __restrict__ O,
    float* __restrict__ Opart, float* __restrict__ mlbuf)
{
    __shared__ __bf16 Kl[2][64 * 64];                  // swizzled, 8KB each
    __shared__ __bf16 Vl[3][64 * 64];                  // swizzled, 8KB each
    __shared__ __align__(16) unsigned char plds[4][2048];

    const int tid  = threadIdx.x;
    const int lane = tid & 63;
    const int col  = lane & 15;
    const int g    = lane >> 4;
    const int w    = tid >> 6;

    const int n   = blockIdx.x;
    const int b   = n & 7;
    const int idx = n >> 3;
    int qt, j0, j1, ch;
    bool partial;
    if (idx < 32)      { qt = 32 + idx;  j0 = 0;  j1 = 32;     partial = true;  ch = 0; }
    else if (idx < 64) { qt = idx;       j0 = 32; j1 = qt + 1; partial = true;  ch = 1; }
    else               { qt = 95 - idx;  j0 = 0;  j1 = qt + 1; partial = false; ch = 0; }

    const int qloc = qt * 64 + w * 16 + col;           // lane's q row in sequence
    const size_t qrow = (size_t)b * TT + qloc;
    bf16x8 qb[2];
#pragma unroll
    for (int s = 0; s < 2; s++)
        qb[s] = *(const bf16x8*)(Q + qrow * HS + s * 32 + g * 8);

    // stage-thread geometry: thread handles 16B chunks (r0,c0),(r1,c0)
    const int r0 = tid >> 3, c0 = tid & 7;
    const int r1 = r0 + 32;
    const __bf16* Kbase = K + (size_t)b * TT * HS;
    const __bf16* Vbase = Vt + (size_t)b * 64 * TT;

#define SWZ(row, cb) (((row) << 6) | (((cb) ^ ((row) & 7)) << 3))

    f32x4 acc[4];
#pragma unroll
    for (int i = 0; i < 4; i++) acc[i] = 0.f;
    float mrun = -3e38f;
    float lsum0 = 0.f, lsum1 = 0.f, lsum2 = 0.f, lsum3 = 0.f;

    unsigned char* pbase = plds[w] + col * 128;
    const int sw = col & 7;

    bf16x8 sk0, sk1, sv0, sv1;                          // staging registers
    auto stageLoad = [&](int j) {
        const __bf16* kp = Kbase + (size_t)(j * 64) * HS;
        sk0 = *(const bf16x8*)(kp + r0 * HS + c0 * 8);
        sk1 = *(const bf16x8*)(kp + r1 * HS + c0 * 8);
        const __bf16* vp = Vbase + j * 64;
        sv0 = *(const bf16x8*)(vp + (size_t)r0 * TT + c0 * 8);
        sv1 = *(const bf16x8*)(vp + (size_t)r1 * TT + c0 * 8);
    };
    auto stageWriteK = [&](int kb) {
        *(bf16x8*)&Kl[kb][SWZ(r0, c0)] = sk0;
        *(bf16x8*)&Kl[kb][SWZ(r1, c0)] = sk1;
    };
    auto stageWriteV = [&](int vb) {
        *(bf16x8*)&Vl[vb][SWZ(r0, c0)] = sv0;
        *(bf16x8*)&Vl[vb][SWZ(r1, c0)] = sv1;
    };

    f32x4 sfA[4], sfB[4];

    // QK phase: S^T(tile jv) from Kl[jv&1] into SF (no consumer this iter)
    auto qkPhase = [&](int jv, f32x4 (&SF)[4]) {
        bf16x8 kf[8];
#pragma unroll
        for (int nf = 0; nf < 4; nf++)
#pragma unroll
            for (int s = 0; s < 2; s++)
                kf[nf * 2 + s] = *(const bf16x8*)&Kl[jv & 1][SWZ(nf * 16 + col, s * 4 + g)];
        __builtin_amdgcn_s_setprio(1);
#pragma unroll
        for (int s = 0; s < 2; s++)
#pragma unroll
            for (int nf = 0; nf < 4; nf++)
                SF[nf] = __builtin_amdgcn_mfma_f32_16x16x32_bf16(kf[nf * 2 + s], qb[s], SF[nf], 0, 0, 0);
        __builtin_amdgcn_s_setprio(0);
    };

    // finish phase: softmax + PV of tile jv (V in Vl[vb])
    auto finPhase = [&](int jv, f32x4 (&SF)[4], int vb) {
        bf16x8 vf[8];
#pragma unroll
        for (int nf = 0; nf < 4; nf++)
#pragma unroll
            for (int s = 0; s < 2; s++)
                vf[nf * 2 + s] = *(const bf16x8*)&Vl[vb][SWZ(nf * 16 + col, s * 4 + g)];
        if (jv == qt) {                                 // causal mask (diag only)
#pragma unroll
            for (int nf = 0; nf < 4; nf++)
#pragma unroll
                for (int r = 0; r < 4; r++)
                    if (jv * 64 + nf * 16 + g * 4 + r > qloc) SF[nf][r] = -3e38f;
        }
        float fm[4];
#pragma unroll
        for (int f = 0; f < 4; f++)
            fm[f] = fmaxf(fmaxf(SF[f][0], SF[f][1]), fmaxf(SF[f][2], SF[f][3]));
        float mt = fmaxf(fmaxf(fm[0], fm[1]), fmaxf(fm[2], fm[3]));
        if (!__all(mt <= mrun + 8.0f)) {                // defer-max (THR=8)
            float mg = fmaxf(mt, __shfl_xor(mt, 16));
            mg = fmaxf(mg, __shfl_xor(mg, 32));
            float mn = fmaxf(mrun, mg);
            float al = exp2f(mrun - mn);
            mrun = mn;
            lsum0 *= al; lsum1 *= al; lsum2 *= al; lsum3 *= al;
#pragma unroll
            for (int nf = 0; nf < 4; nf++) acc[nf] *= al;
        }
#pragma unroll
        for (int f = 0; f < 4; f++) {
            float p0 = exp2f(SF[f][0] - mrun);
            float p1 = exp2f(SF[f][1] - mrun);
            float p2 = exp2f(SF[f][2] - mrun);
            float p3 = exp2f(SF[f][3] - mrun);
            SF[f][0] = p0; SF[f][1] = p1; SF[f][2] = p2; SF[f][3] = p3;
            lsum0 += p0; lsum1 += p1; lsum2 += p2; lsum3 += p3;
        }
#pragma unroll
        for (int nf = 0; nf < 4; nf++) {                // P^T -> P rows (bounce)
            uint2 val;
            val.x = pack_bf16(SF[nf][0], SF[nf][1]);
            val.y = pack_bf16(SF[nf][2], SF[nf][3]);
            *(uint2*)(pbase + ((((nf * 2 + (g >> 1)) ^ sw) << 4) | ((g & 1) << 3))) = val;
        }
        __builtin_amdgcn_s_setprio(1);
#pragma unroll
        for (int s = 0; s < 2; s++) {
            bf16x8 pf = *(const bf16x8*)(pbase + (((s * 4 + g) ^ sw) << 4));
#pragma unroll
            for (int nf = 0; nf < 4; nf++)
                acc[nf] = __builtin_amdgcn_mfma_f32_16x16x32_bf16(vf[nf * 2 + s], pf, acc[nf], 0, 0, 0);
        }
        __builtin_amdgcn_s_setprio(0);
    };

    // one pipelined step: QK(jv) into SFq, finish(jv-1) from SFf
    auto iterStep = [&](int jv, f32x4 (&SFq)[4], f32x4 (&SFf)[4], int vb_f) {
        const bool more = (jv + 1 < j1);
        if (more) stageLoad(jv + 1);
        __builtin_amdgcn_sched_barrier(0);
#pragma unroll
        for (int i = 0; i < 4; i++) SFq[i] = 0.f;
        qkPhase(jv, SFq);
        finPhase(jv - 1, SFf, vb_f);
        if (more) {
            stageWriteK((jv + 1) & 1);
            stageWriteV(vb_f + 2 >= 3 ? vb_f - 1 : vb_f + 2);
        }
        __syncthreads();
    };

    // ---- prologue: stage tile j0 ----
    stageLoad(j0);
    stageWriteK(j0 & 1);
    const int vb0 = j0 % 3;                             // 0 for j0=0, 2 for j0=32
    stageWriteV(vb0);
    __syncthreads();

    // ---- iter0: QK(j0) only, stage j0+1 ----
    {
        const bool more = (j0 + 1 < j1);
        if (more) stageLoad(j0 + 1);
        __builtin_amdgcn_sched_barrier(0);
#pragma unroll
        for (int i = 0; i < 4; i++) sfA[i] = 0.f;
        qkPhase(j0, sfA);
        if (more) {
            stageWriteK((j0 + 1) & 1);
            stageWriteV(vb0 + 1 >= 3 ? vb0 - 2 : vb0 + 1);
        }
        __syncthreads();
    }

    int vb_f = vb0;                                     // V buffer of tile j0
    int jv = j0 + 1;
    while (jv + 1 < j1) {
        iterStep(jv, sfB, sfA, vb_f);
        vb_f = (vb_f + 1 >= 3) ? vb_f - 2 : vb_f + 1;
        iterStep(jv + 1, sfA, sfB, vb_f);
        vb_f = (vb_f + 1 >= 3) ? vb_f - 2 : vb_f + 1;
        jv += 2;
    }
    bool lastIsB = false;
    if (jv < j1) {                                      // one leftover step
        iterStep(jv, sfB, sfA, vb_f);
        vb_f = (vb_f + 1 >= 3) ? vb_f - 2 : vb_f + 1;
        lastIsB = true;
    }
    // ---- final finish of tile j1-1 ----
    if (lastIsB) finPhase(j1 - 1, sfB, vb_f);
    else         finPhase(j1 - 1, sfA, vb_f);

    // ---- final l combine across lane-groups ----
    float ls = (lsum0 + lsum1) + (lsum2 + lsum3);
    ls += __shfl_xor(ls, 16);
    ls += __shfl_xor(ls, 32);

    if (!partial) {
        float rinv = __builtin_amdgcn_rcpf(ls);
        float* orow = O + qrow * HS;
#pragma unroll
        for (int nf = 0; nf < 4; nf++) {
            float4 v;
            v.x = acc[nf][0] * rinv; v.y = acc[nf][1] * rinv;
            v.z = acc[nf][2] * rinv; v.w = acc[nf][3] * rinv;
            *(float4*)(orow + nf * 16 + g * 4) = v;
        }
    } else {
        const int slot = (b * 32 + (qt - 32)) * 2 + ch;
        float* prow = Opart + ((size_t)slot * 64 + w * 16 + col) * 64;
#pragma unroll
        for (int nf = 0; nf < 4; nf++) {
            float4 v;
            v.x = acc[nf][0]; v.y = acc[nf][1];
            v.z = acc[nf][2]; v.w = acc[nf][3];
            *(float4*)(prow + nf * 16 + g * 4) = v;
        }
        if (g == 0) {
            float2 mv = make_float2(mrun, ls);
            *(float2*)(mlbuf + ((size_t)slot * 64 + w * 16 + col) * 2) = mv;
        }
    }
#undef SWZ
}

// ---------------------------------------------------------------------------
// Kernel 3: combine the two split-K partials for qt in [32,64).
// ---------------------------------------------------------------------------
__global__ __launch_bounds__(256) void combine_kernel(
    const float* __restrict__ Opart, const float* __restrict__ mlbuf,
    float* __restrict__ O)
{
    const int qi = blockIdx.x;             // 0..31 -> qt = 32+qi
    const int b  = blockIdx.y;
    const int row = threadIdx.x >> 2;
    const int seg = threadIdx.x & 3;
    const int slot0 = (b * 32 + qi) * 2;

    const float* p0 = mlbuf + ((size_t)slot0 * 64 + row) * 2;
    const float* p1 = mlbuf + ((size_t)(slot0 + 1) * 64 + row) * 2;
    float m0 = p0[0], l0 = p0[1];
    float m1 = p1[0], l1 = p1[1];
    float M  = fmaxf(m0, m1);
    float w0 = exp2f(m0 - M), w1 = exp2f(m1 - M);
    float rinv = 1.0f / (l0 * w0 + l1 * w1);
    w0 *= rinv; w1 *= rinv;

    const float4* s0 = (const float4*)(Opart + ((size_t)slot0 * 64 + row) * 64 + seg * 16);
    const float4* s1 = (const float4*)(Opart + ((size_t)(slot0 + 1) * 64 + row) * 64 + seg * 16);
    float4* dst = (float4*)(O + ((size_t)b * TT + (32 + qi) * 64 + row) * 64 + seg * 16);
#pragma unroll
    for (int i = 0; i < 4; i++) {
        float4 a = s0[i], c = s1[i];
        float4 v;
        v.x = a.x * w0 + c.x * w1;
        v.y = a.y * w0 + c.y * w1;
        v.z = a.z * w0 + c.z * w1;
        v.w = a.w * w0 + c.w * w1;
        dst[i] = v;
    }
}

// ---------------------------------------------------------------------------
extern "C" void kernel_launch(void* const* d_in, const int* in_sizes, int n_in,
                              void* d_out, int out_size, void* d_ws, size_t ws_size,
                              hipStream_t stream)
{
    const float* x    = (const float*)d_in[0];
    const float* cosT = (const float*)d_in[1];
    const float* sinT = (const float*)d_in[2];
    const float* Wq   = (const float*)d_in[3];
    const float* Wk   = (const float*)d_in[4];
    const float* Wv   = (const float*)d_in[5];
    float* out = (float*)d_out;

    __bf16* Qb = (__bf16*)d_ws;
    __bf16* Kb = Qb + (size_t)BB * TT * HS;
    __bf16* Vb = Kb + (size_t)BB * TT * HS;   // transposed: [b*64+d][t]
    __bf16* Wt = Vb + (size_t)BB * TT * HS;

    const size_t base_bytes = (size_t)3 * BB * TT * HS * 2 + 192 * 1024 * 2;
    float* Opart = (float*)((char*)d_ws + ((base_bytes + 255) & ~(size_t)255));
    float* mlbuf = Opart + (size_t)8 * 32 * 2 * 64 * 64;   // 8.4 MB of partials

    wprep_kernel<<<(192 * 1024) / 256, 256, 0, stream>>>(Wq, Wk, Wv, Wt);
    qkv_rope_kernel<<<(BB * TT) / 64, 256, 0, stream>>>(x, cosT, sinT, Wt, Qb, Kb, Vb);
    attn_kernel<<<768, 256, 0, stream>>>(Qb, Kb, Vb, out, Opart, mlbuf);
    combine_kernel<<<dim3(32, 8), 256, 0, stream>>>(Opart, mlbuf, out);
}